// Round 3
// baseline (554.923 us; speedup 1.0000x reference)
//
#include <hip/hip_runtime.h>
#include <math.h>

#define BATCHN 65536
#define INPUTN 128
#define HIDDENN 512
#define CATN 640
#define KT 64            // k-tile size
#define NT 10            // number of k-tiles (640/64)
#define RPB 64           // rows per k_proj block
#define LDSS 68          // padded LDS row stride (68*4=272 B, 16B-aligned, conflict-free)
#define ROWS_LSTM 32

// ---------------------------------------------------------------------------
// Kernel 0: build the fixed 16x16 unitary U_g per gate (batch-independent part
// of the circuit). Thread t = (g<<4)|col simulates basis state |col>.
// ---------------------------------------------------------------------------
__global__ void k_build_u(const float* __restrict__ qwF, const float* __restrict__ qwI,
                          const float* __restrict__ qwO, const float* __restrict__ qwC,
                          float2* __restrict__ U) {
  int t = threadIdx.x;
  if (t >= 64) return;
  int g = t >> 4, col = t & 15;
  const float* qw = (g == 0) ? qwF : (g == 1) ? qwI : (g == 2) ? qwO : qwC;

  float sr[16], si[16];
#pragma unroll
  for (int i = 0; i < 16; i++) { sr[i] = (i == col) ? 1.f : 0.f; si[i] = 0.f; }

#pragma unroll
  for (int l = 0; l < 2; l++) {
#pragma unroll
    for (int j = 0; j < 4; j++) {
      const int bc = 8 >> j;
      const int bt = 8 >> ((j + 1) & 3);
      float tr[16], ti[16];
#pragma unroll
      for (int i = 0; i < 16; i++) {
        int src = (i & bc) ? (i ^ bt) : i;
        tr[i] = sr[src]; ti[i] = si[src];
      }
#pragma unroll
      for (int i = 0; i < 16; i++) { sr[i] = tr[i]; si[i] = ti[i]; }
    }
#pragma unroll
    for (int j = 0; j < 4; j++) {
      const int bit = 8 >> j;
      const float thx = qw[(l * 4 + j) * 3 + 0] * 0.5f;
      const float thy = qw[(l * 4 + j) * 3 + 1] * 0.5f;
      const float thz = qw[(l * 4 + j) * 3 + 2] * 0.5f;
      float c, s;
      c = cosf(thx); s = sinf(thx);           // RX
#pragma unroll
      for (int i = 0; i < 16; i++) if (!(i & bit)) {
        const int k2 = i | bit;
        const float ar = sr[i], ai = si[i], br = sr[k2], bi = si[k2];
        sr[i]  = c * ar + s * bi;  si[i]  = c * ai - s * br;
        sr[k2] = c * br + s * ai;  si[k2] = c * bi - s * ar;
      }
      c = cosf(thy); s = sinf(thy);           // RY
#pragma unroll
      for (int i = 0; i < 16; i++) if (!(i & bit)) {
        const int k2 = i | bit;
        const float ar = sr[i], ai = si[i], br = sr[k2], bi = si[k2];
        sr[i]  = c * ar - s * br;  si[i]  = c * ai - s * bi;
        sr[k2] = s * ar + c * br;  si[k2] = s * ai + c * bi;
      }
      c = cosf(thz); s = sinf(thz);           // RZ
#pragma unroll
      for (int i = 0; i < 16; i++) if (!(i & bit)) {
        const int k2 = i | bit;
        const float ar = sr[i], ai = si[i], br = sr[k2], bi = si[k2];
        sr[i]  = c * ar + s * ai;  si[i]  = c * ai - s * ar;
        sr[k2] = c * br - s * bi;  si[k2] = c * bi + s * br;
      }
    }
  }
#pragma unroll
  for (int m = 0; m < 16; m++)
    U[(g * 16 + m) * 16 + col] = make_float2(sr[m], si[m]);
}

// ---------------------------------------------------------------------------
// Kernel 1: block = 64 rows x 4 gates (256 threads). x|h row data is staged
// through LDS with fully coalesced global loads and a padded [64][68] layout
// (both ds_write_b128 and ds_read_b128 phases hit all 32 banks). Double-
// buffered, register-prefetched, one barrier per k-tile. Each row is read
// from HBM exactly once (160 MB total). Weight loads are wave-uniform via
// readfirstlane(gate) -> scalar K$ loads.
// ---------------------------------------------------------------------------
__global__ __launch_bounds__(256) void k_proj_q(
    const float* __restrict__ x, const float* __restrict__ hprev,
    const float* __restrict__ pwF, const float* __restrict__ pbF,
    const float* __restrict__ pwI, const float* __restrict__ pbI,
    const float* __restrict__ pwO, const float* __restrict__ pbO,
    const float* __restrict__ pwC, const float* __restrict__ pbC,
    const float2* __restrict__ U, float* __restrict__ qv) {
  __shared__ float lds[2][RPB][LDSS];
  const int tid = threadIdx.x;
  const int rb = blockIdx.x * RPB;
  const int c4 = tid & 15;          // staging: 16 float4-columns
  const int r0 = tid >> 4;          // staging: base row 0..15
  const int row = tid & 63;         // compute: row within block
  const int g = __builtin_amdgcn_readfirstlane(tid >> 6);   // wave-uniform gate

  const float* pw = (g == 0) ? pwF : (g == 1) ? pwI : (g == 2) ? pwO : pwC;
  const float* pb = (g == 0) ? pbF : (g == 1) ? pbI : (g == 2) ? pbO : pbC;

  float acc0 = pb[0], acc1 = pb[1], acc2 = pb[2], acc3 = pb[3];

  float4 nv[4];
  // prologue: stage tile 0 (k 0..63, from x)
#pragma unroll
  for (int p = 0; p < 4; ++p)
    nv[p] = *(const float4*)(x + (size_t)(rb + r0 + p * 16) * INPUTN + c4 * 4);
#pragma unroll
  for (int p = 0; p < 4; ++p)
    *(float4*)&lds[0][r0 + p * 16][c4 * 4] = nv[p];
  __syncthreads();

#pragma unroll
  for (int T = 0; T < NT; ++T) {
    if (T + 1 < NT) {
      const int gk = (T + 1) * KT + c4 * 4;
#pragma unroll
      for (int p = 0; p < 4; ++p) {
        const int grow = rb + r0 + p * 16;
        const float* src = (gk < INPUTN)
            ? (x + (size_t)grow * INPUTN + gk)
            : (hprev + (size_t)grow * HIDDENN + (gk - INPUTN));
        nv[p] = *(const float4*)src;
      }
    }
    const float* wbase = pw + T * KT;
#pragma unroll
    for (int k4 = 0; k4 < KT / 4; ++k4) {
      const float4 a  = *(const float4*)&lds[T & 1][row][k4 * 4];
      const float4 w0 = *(const float4*)(wbase + 0 * CATN + k4 * 4);
      const float4 w1 = *(const float4*)(wbase + 1 * CATN + k4 * 4);
      const float4 w2 = *(const float4*)(wbase + 2 * CATN + k4 * 4);
      const float4 w3 = *(const float4*)(wbase + 3 * CATN + k4 * 4);
      acc0 += a.x * w0.x + a.y * w0.y + a.z * w0.z + a.w * w0.w;
      acc1 += a.x * w1.x + a.y * w1.y + a.z * w1.z + a.w * w1.w;
      acc2 += a.x * w2.x + a.y * w2.y + a.z * w2.z + a.w * w2.w;
      acc3 += a.x * w3.x + a.y * w3.y + a.z * w3.z + a.w * w3.w;
    }
    if (T + 1 < NT) {
#pragma unroll
      for (int p = 0; p < 4; ++p)
        *(float4*)&lds[(T + 1) & 1][r0 + p * 16][c4 * 4] = nv[p];
      __syncthreads();
    }
  }

  // quantum part for (row, gate)
  float cs[4], sn[4];
  float acc[4] = {acc0, acc1, acc2, acc3};
#pragma unroll
  for (int j = 0; j < 4; j++) __sincosf(acc[j] * 0.5f, &sn[j], &cs[j]);
  float psi[16];
#pragma unroll
  for (int c16 = 0; c16 < 16; c16++) {
    float p = ((c16 & 8) ? sn[0] : cs[0]);
    p *= ((c16 & 4) ? sn[1] : cs[1]);
    p *= ((c16 & 2) ? sn[2] : cs[2]);
    p *= ((c16 & 1) ? sn[3] : cs[3]);
    psi[c16] = p;
  }
  const float2* Ug = U + g * 256;
  float q0 = 0.f, q1 = 0.f, q2 = 0.f, q3 = 0.f;
#pragma unroll
  for (int m = 0; m < 16; m++) {
    float ssr = 0.f, ssi = 0.f;
#pragma unroll
    for (int c16 = 0; c16 < 16; c16++) {
      const float2 u = Ug[m * 16 + c16];
      ssr += u.x * psi[c16];
      ssi += u.y * psi[c16];
    }
    const float p = ssr * ssr + ssi * ssi;
    q0 = (m & 8) ? q0 - p : q0 + p;
    q1 = (m & 4) ? q1 - p : q1 + p;
    q2 = (m & 2) ? q2 - p : q2 + p;
    q3 = (m & 1) ? q3 - p : q3 + p;
  }
  *(float4*)(qv + (size_t)(rb + row) * 16 + g * 4) = make_float4(q0, q1, q2, q3);
}

// ---------------------------------------------------------------------------
// Kernel 2: LSTM expansion. Thread owns h-positions {tid, tid+256}: weight
// setup is perfectly coalesced (consecutive float4 per lane), streaming loads
// and stores are coalesced scalar accesses, weights/biases live in ~70 VGPRs
// (7 waves/SIMD). 32 rows per block; q loads are block-uniform scalar loads.
// ---------------------------------------------------------------------------
__device__ __forceinline__ float sigmf(float v) {
  return __builtin_amdgcn_rcpf(1.f + __expf(-v));
}
__device__ __forceinline__ float tanhfast(float v) {
  return 1.f - 2.f * __builtin_amdgcn_rcpf(__expf(2.f * v) + 1.f);
}

__global__ __launch_bounds__(256) void k_lstm(
    const float* __restrict__ qv, const float* __restrict__ cprev,
    const float* __restrict__ lwF, const float* __restrict__ lbF,
    const float* __restrict__ lwI, const float* __restrict__ lbI,
    const float* __restrict__ lwO, const float* __restrict__ lbO,
    const float* __restrict__ lwC, const float* __restrict__ lbC,
    float* __restrict__ out) {
  const int tid = threadIdx.x;
  const int rb = blockIdx.x * ROWS_LSTM;

  float4 wF[2], wI[2], wO[2], wC[2];
  float bFv[2], bIv[2], bOv[2], bCv[2];
#pragma unroll
  for (int hh = 0; hh < 2; ++hh) {
    const int hp = tid + hh * 256;
    wF[hh] = *(const float4*)(lwF + (size_t)hp * 4);
    wI[hh] = *(const float4*)(lwI + (size_t)hp * 4);
    wO[hh] = *(const float4*)(lwO + (size_t)hp * 4);
    wC[hh] = *(const float4*)(lwC + (size_t)hp * 4);
    bFv[hh] = lbF[hp]; bIv[hh] = lbI[hp]; bOv[hh] = lbO[hp]; bCv[hh] = lbC[hp];
  }

#pragma unroll 2
  for (int it = 0; it < ROWS_LSTM; ++it) {
    const int r = rb + it;
    const float* q = qv + (size_t)r * 16;     // block-uniform -> scalar loads
    const float4 qF = *(const float4*)(q);
    const float4 qI = *(const float4*)(q + 4);
    const float4 qO = *(const float4*)(q + 8);
    const float4 qC = *(const float4*)(q + 12);

#pragma unroll
    for (int hh = 0; hh < 2; ++hh) {
      const int hp = tid + hh * 256;
      const float cp = cprev[(size_t)r * HIDDENN + hp];
      const float pf = bFv[hh] + wF[hh].x * qF.x + wF[hh].y * qF.y + wF[hh].z * qF.z + wF[hh].w * qF.w;
      const float pi = bIv[hh] + wI[hh].x * qI.x + wI[hh].y * qI.y + wI[hh].z * qI.z + wI[hh].w * qI.w;
      const float po = bOv[hh] + wO[hh].x * qO.x + wO[hh].y * qO.y + wO[hh].z * qO.z + wO[hh].w * qO.w;
      const float pg = bCv[hh] + wC[hh].x * qC.x + wC[hh].y * qC.y + wC[hh].z * qC.z + wC[hh].w * qC.w;
      const float f  = sigmf(pf);
      const float ii = sigmf(pi);
      const float oo = sigmf(po);
      const float gg = tanhfast(pg);
      const float cc = f * cp + ii * gg;
      out[(size_t)r * HIDDENN + hp] = oo * tanhfast(cc);
      out[(size_t)BATCHN * HIDDENN + (size_t)r * HIDDENN + hp] = cc;
    }
  }
}

// ---------------------------------------------------------------------------
extern "C" void kernel_launch(void* const* d_in, const int* in_sizes, int n_in,
                              void* d_out, int out_size, void* d_ws, size_t ws_size,
                              hipStream_t stream) {
  const float* x  = (const float*)d_in[0];
  const float* h  = (const float*)d_in[1];
  const float* c  = (const float*)d_in[2];
  const float* pwF = (const float*)d_in[3];
  const float* pbF = (const float*)d_in[4];
  const float* qwF = (const float*)d_in[5];
  const float* lwF = (const float*)d_in[6];
  const float* lbF = (const float*)d_in[7];
  const float* pwI = (const float*)d_in[8];
  const float* pbI = (const float*)d_in[9];
  const float* qwI = (const float*)d_in[10];
  const float* lwI = (const float*)d_in[11];
  const float* lbI = (const float*)d_in[12];
  const float* pwO = (const float*)d_in[13];
  const float* pbO = (const float*)d_in[14];
  const float* qwO = (const float*)d_in[15];
  const float* lwO = (const float*)d_in[16];
  const float* lbO = (const float*)d_in[17];
  const float* pwC = (const float*)d_in[18];
  const float* pbC = (const float*)d_in[19];
  const float* qwC = (const float*)d_in[20];
  const float* lwC = (const float*)d_in[21];
  const float* lbC = (const float*)d_in[22];

  float* ws = (float*)d_ws;
  float* qv = ws;                                  // BATCHN*16 floats (4 MB)
  float2* U = (float2*)(ws + (size_t)BATCHN * 16); // 4*16*16 float2 (8 KB)

  k_build_u<<<dim3(1), dim3(64), 0, stream>>>(qwF, qwI, qwO, qwC, U);
  k_proj_q<<<dim3(BATCHN / RPB), dim3(256), 0, stream>>>(x, h, pwF, pbF, pwI, pbI,
                                                         pwO, pbO, pwC, pbC, U, qv);
  k_lstm<<<dim3(BATCHN / ROWS_LSTM), dim3(256), 0, stream>>>(qv, c, lwF, lbF, lwI, lbI,
                                                             lwO, lbO, lwC, lbC,
                                                             (float*)d_out);
}

// Round 4
// 169.179 us; speedup vs baseline: 3.2801x; 3.2801x over previous
//
#include <hip/hip_runtime.h>
#include <math.h>

#define BATCHN 65536
#define INPUTN 128
#define HIDDENN 512
#define CATN 640
#define KT 64            // k-tile size
#define NT 10            // number of k-tiles (640/64)
#define RPB 64           // rows per k_proj block
#define LDSS 68          // padded LDS row stride (272 B: 16B-aligned, conflict-free)
#define ROWS_LSTM 32

// ---------------------------------------------------------------------------
// Kernel 0: build the fixed 16x16 unitary U_g per gate (batch-independent part
// of the circuit). Thread t = (g<<4)|col simulates basis state |col>.
// ---------------------------------------------------------------------------
__global__ void k_build_u(const float* __restrict__ qwF, const float* __restrict__ qwI,
                          const float* __restrict__ qwO, const float* __restrict__ qwC,
                          float2* __restrict__ U) {
  int t = threadIdx.x;
  if (t >= 64) return;
  int g = t >> 4, col = t & 15;
  const float* qw = (g == 0) ? qwF : (g == 1) ? qwI : (g == 2) ? qwO : qwC;

  float sr[16], si[16];
#pragma unroll
  for (int i = 0; i < 16; i++) { sr[i] = (i == col) ? 1.f : 0.f; si[i] = 0.f; }

#pragma unroll
  for (int l = 0; l < 2; l++) {
#pragma unroll
    for (int j = 0; j < 4; j++) {
      const int bc = 8 >> j;
      const int bt = 8 >> ((j + 1) & 3);
      float tr[16], ti[16];
#pragma unroll
      for (int i = 0; i < 16; i++) {
        int src = (i & bc) ? (i ^ bt) : i;
        tr[i] = sr[src]; ti[i] = si[src];
      }
#pragma unroll
      for (int i = 0; i < 16; i++) { sr[i] = tr[i]; si[i] = ti[i]; }
    }
#pragma unroll
    for (int j = 0; j < 4; j++) {
      const int bit = 8 >> j;
      const float thx = qw[(l * 4 + j) * 3 + 0] * 0.5f;
      const float thy = qw[(l * 4 + j) * 3 + 1] * 0.5f;
      const float thz = qw[(l * 4 + j) * 3 + 2] * 0.5f;
      float c, s;
      c = cosf(thx); s = sinf(thx);           // RX
#pragma unroll
      for (int i = 0; i < 16; i++) if (!(i & bit)) {
        const int k2 = i | bit;
        const float ar = sr[i], ai = si[i], br = sr[k2], bi = si[k2];
        sr[i]  = c * ar + s * bi;  si[i]  = c * ai - s * br;
        sr[k2] = c * br + s * ai;  si[k2] = c * bi - s * ar;
      }
      c = cosf(thy); s = sinf(thy);           // RY
#pragma unroll
      for (int i = 0; i < 16; i++) if (!(i & bit)) {
        const int k2 = i | bit;
        const float ar = sr[i], ai = si[i], br = sr[k2], bi = si[k2];
        sr[i]  = c * ar - s * br;  si[i]  = c * ai - s * bi;
        sr[k2] = s * ar + c * br;  si[k2] = s * ai + c * bi;
      }
      c = cosf(thz); s = sinf(thz);           // RZ
#pragma unroll
      for (int i = 0; i < 16; i++) if (!(i & bit)) {
        const int k2 = i | bit;
        const float ar = sr[i], ai = si[i], br = sr[k2], bi = si[k2];
        sr[i]  = c * ar + s * ai;  si[i]  = c * ai - s * ar;
        sr[k2] = c * br - s * bi;  si[k2] = c * bi + s * br;
      }
    }
  }
#pragma unroll
  for (int m = 0; m < 16; m++)
    U[(g * 16 + m) * 16 + col] = make_float2(sr[m], si[m]);
}

// ---------------------------------------------------------------------------
// Kernel 1: block = 64 rows x 4 gates (256 threads). Row data staged through a
// padded [64][68] LDS tile with coalesced global loads; each row read from HBM
// exactly once. Double-buffered, 1 barrier/tile. Tile loop is NOT unrolled
// (round-3 full unroll spilled: 256 VGPR, 373 MB scratch writes). Weight loads
// are wave-uniform (readfirstlane'd gate) -> scalar K$ loads.
// ---------------------------------------------------------------------------
__global__ __launch_bounds__(256) void k_proj_q(
    const float* __restrict__ x, const float* __restrict__ hprev,
    const float* __restrict__ pwF, const float* __restrict__ pbF,
    const float* __restrict__ pwI, const float* __restrict__ pbI,
    const float* __restrict__ pwO, const float* __restrict__ pbO,
    const float* __restrict__ pwC, const float* __restrict__ pbC,
    const float2* __restrict__ U, float* __restrict__ qv) {
  __shared__ float lds[2][RPB][LDSS];
  const int tid = threadIdx.x;
  const int rb = blockIdx.x * RPB;
  const int c4 = tid & 15;          // staging: 16 float4-columns
  const int r0 = tid >> 4;          // staging: base row 0..15
  const int row = tid & 63;         // compute: row within block
  const int g = __builtin_amdgcn_readfirstlane(tid >> 6);   // wave-uniform gate

  const float* pw = (g == 0) ? pwF : (g == 1) ? pwI : (g == 2) ? pwO : pwC;
  const float* pb = (g == 0) ? pbF : (g == 1) ? pbI : (g == 2) ? pbO : pbC;

  float acc0 = pb[0], acc1 = pb[1], acc2 = pb[2], acc3 = pb[3];

  // prologue: stage tile 0 (k 0..63, from x)
  {
    float4 pv[4];
#pragma unroll
    for (int p = 0; p < 4; ++p)
      pv[p] = *(const float4*)(x + (size_t)(rb + r0 + p * 16) * INPUTN + c4 * 4);
#pragma unroll
    for (int p = 0; p < 4; ++p)
      *(float4*)&lds[0][r0 + p * 16][c4 * 4] = pv[p];
  }
  __syncthreads();

#pragma unroll 1
  for (int T = 0; T < NT; ++T) {
    float4 nv0, nv1, nv2, nv3;
    const bool more = (T + 1 < NT);
    if (more) {
      const int gk = (T + 1) * KT + c4 * 4;
      const float* base = (gk < INPUTN) ? (x + gk) : (hprev + (gk - INPUTN));
      const size_t stride = (gk < INPUTN) ? INPUTN : HIDDENN;
      nv0 = *(const float4*)(base + (size_t)(rb + r0 +  0) * stride);
      nv1 = *(const float4*)(base + (size_t)(rb + r0 + 16) * stride);
      nv2 = *(const float4*)(base + (size_t)(rb + r0 + 32) * stride);
      nv3 = *(const float4*)(base + (size_t)(rb + r0 + 48) * stride);
    }
    const float* arow = &lds[T & 1][row][0];
    const float* wbase = pw + T * KT;
#pragma unroll
    for (int k4 = 0; k4 < KT / 4; ++k4) {
      const float4 a  = *(const float4*)(arow + k4 * 4);
      const float4 w0 = *(const float4*)(wbase + 0 * CATN + k4 * 4);
      const float4 w1 = *(const float4*)(wbase + 1 * CATN + k4 * 4);
      const float4 w2 = *(const float4*)(wbase + 2 * CATN + k4 * 4);
      const float4 w3 = *(const float4*)(wbase + 3 * CATN + k4 * 4);
      acc0 += a.x * w0.x + a.y * w0.y + a.z * w0.z + a.w * w0.w;
      acc1 += a.x * w1.x + a.y * w1.y + a.z * w1.z + a.w * w1.w;
      acc2 += a.x * w2.x + a.y * w2.y + a.z * w2.z + a.w * w2.w;
      acc3 += a.x * w3.x + a.y * w3.y + a.z * w3.z + a.w * w3.w;
    }
    if (more) {
      float* dst = &lds[(T + 1) & 1][r0][c4 * 4];
      *(float4*)(dst + 0 * 16 * LDSS) = nv0;
      *(float4*)(dst + 1 * 16 * LDSS) = nv1;
      *(float4*)(dst + 2 * 16 * LDSS) = nv2;
      *(float4*)(dst + 3 * 16 * LDSS) = nv3;
      __syncthreads();
    }
  }

  // quantum part for (row, gate)
  float cs[4], sn[4];
  float acc[4] = {acc0, acc1, acc2, acc3};
#pragma unroll
  for (int j = 0; j < 4; j++) __sincosf(acc[j] * 0.5f, &sn[j], &cs[j]);
  float psi[16];
#pragma unroll
  for (int c16 = 0; c16 < 16; c16++) {
    float p = ((c16 & 8) ? sn[0] : cs[0]);
    p *= ((c16 & 4) ? sn[1] : cs[1]);
    p *= ((c16 & 2) ? sn[2] : cs[2]);
    p *= ((c16 & 1) ? sn[3] : cs[3]);
    psi[c16] = p;
  }
  const float2* Ug = U + g * 256;
  float q0 = 0.f, q1 = 0.f, q2 = 0.f, q3 = 0.f;
#pragma unroll
  for (int m = 0; m < 16; m++) {
    float ssr = 0.f, ssi = 0.f;
#pragma unroll
    for (int c16 = 0; c16 < 16; c16++) {
      const float2 u = Ug[m * 16 + c16];
      ssr += u.x * psi[c16];
      ssi += u.y * psi[c16];
    }
    const float p = ssr * ssr + ssi * ssi;
    q0 = (m & 8) ? q0 - p : q0 + p;
    q1 = (m & 4) ? q1 - p : q1 + p;
    q2 = (m & 2) ? q2 - p : q2 + p;
    q3 = (m & 1) ? q3 - p : q3 + p;
  }
  *(float4*)(qv + (size_t)(rb + row) * 16 + g * 4) = make_float4(q0, q1, q2, q3);
}

// ---------------------------------------------------------------------------
// Kernel 2: LSTM expansion. Thread owns h-positions {tid, tid+256}; weights/
// biases in registers (coalesced setup), streaming c_prev/out accesses are
// coalesced and nontemporal (no reuse -> don't pollute L2).
// ---------------------------------------------------------------------------
__device__ __forceinline__ float sigmf(float v) {
  return __builtin_amdgcn_rcpf(1.f + __expf(-v));
}
__device__ __forceinline__ float tanhfast(float v) {
  return 1.f - 2.f * __builtin_amdgcn_rcpf(__expf(2.f * v) + 1.f);
}

__global__ __launch_bounds__(256) void k_lstm(
    const float* __restrict__ qv, const float* __restrict__ cprev,
    const float* __restrict__ lwF, const float* __restrict__ lbF,
    const float* __restrict__ lwI, const float* __restrict__ lbI,
    const float* __restrict__ lwO, const float* __restrict__ lbO,
    const float* __restrict__ lwC, const float* __restrict__ lbC,
    float* __restrict__ out) {
  const int tid = threadIdx.x;
  const int rb = blockIdx.x * ROWS_LSTM;

  float4 wF[2], wI[2], wO[2], wC[2];
  float bFv[2], bIv[2], bOv[2], bCv[2];
#pragma unroll
  for (int hh = 0; hh < 2; ++hh) {
    const int hp = tid + hh * 256;
    wF[hh] = *(const float4*)(lwF + (size_t)hp * 4);
    wI[hh] = *(const float4*)(lwI + (size_t)hp * 4);
    wO[hh] = *(const float4*)(lwO + (size_t)hp * 4);
    wC[hh] = *(const float4*)(lwC + (size_t)hp * 4);
    bFv[hh] = lbF[hp]; bIv[hh] = lbI[hp]; bOv[hh] = lbO[hp]; bCv[hh] = lbC[hp];
  }

#pragma unroll 2
  for (int it = 0; it < ROWS_LSTM; ++it) {
    const int r = rb + it;
    const float* q = qv + (size_t)r * 16;     // block-uniform -> scalar loads
    const float4 qF = *(const float4*)(q);
    const float4 qI = *(const float4*)(q + 4);
    const float4 qO = *(const float4*)(q + 8);
    const float4 qC = *(const float4*)(q + 12);

#pragma unroll
    for (int hh = 0; hh < 2; ++hh) {
      const int hp = tid + hh * 256;
      const float cp = __builtin_nontemporal_load(cprev + (size_t)r * HIDDENN + hp);
      const float pf = bFv[hh] + wF[hh].x * qF.x + wF[hh].y * qF.y + wF[hh].z * qF.z + wF[hh].w * qF.w;
      const float pi = bIv[hh] + wI[hh].x * qI.x + wI[hh].y * qI.y + wI[hh].z * qI.z + wI[hh].w * qI.w;
      const float po = bOv[hh] + wO[hh].x * qO.x + wO[hh].y * qO.y + wO[hh].z * qO.z + wO[hh].w * qO.w;
      const float pg = bCv[hh] + wC[hh].x * qC.x + wC[hh].y * qC.y + wC[hh].z * qC.z + wC[hh].w * qC.w;
      const float f  = sigmf(pf);
      const float ii = sigmf(pi);
      const float oo = sigmf(po);
      const float gg = tanhfast(pg);
      const float cc = f * cp + ii * gg;
      __builtin_nontemporal_store(oo * tanhfast(cc), out + (size_t)r * HIDDENN + hp);
      __builtin_nontemporal_store(cc, out + (size_t)BATCHN * HIDDENN + (size_t)r * HIDDENN + hp);
    }
  }
}

// ---------------------------------------------------------------------------
extern "C" void kernel_launch(void* const* d_in, const int* in_sizes, int n_in,
                              void* d_out, int out_size, void* d_ws, size_t ws_size,
                              hipStream_t stream) {
  const float* x  = (const float*)d_in[0];
  const float* h  = (const float*)d_in[1];
  const float* c  = (const float*)d_in[2];
  const float* pwF = (const float*)d_in[3];
  const float* pbF = (const float*)d_in[4];
  const float* qwF = (const float*)d_in[5];
  const float* lwF = (const float*)d_in[6];
  const float* lbF = (const float*)d_in[7];
  const float* pwI = (const float*)d_in[8];
  const float* pbI = (const float*)d_in[9];
  const float* qwI = (const float*)d_in[10];
  const float* lwI = (const float*)d_in[11];
  const float* lbI = (const float*)d_in[12];
  const float* pwO = (const float*)d_in[13];
  const float* pbO = (const float*)d_in[14];
  const float* qwO = (const float*)d_in[15];
  const float* lwO = (const float*)d_in[16];
  const float* lbO = (const float*)d_in[17];
  const float* pwC = (const float*)d_in[18];
  const float* pbC = (const float*)d_in[19];
  const float* qwC = (const float*)d_in[20];
  const float* lwC = (const float*)d_in[21];
  const float* lbC = (const float*)d_in[22];

  float* ws = (float*)d_ws;
  float* qv = ws;                                  // BATCHN*16 floats (4 MB)
  float2* U = (float2*)(ws + (size_t)BATCHN * 16); // 4*16*16 float2 (8 KB)

  k_build_u<<<dim3(1), dim3(64), 0, stream>>>(qwF, qwI, qwO, qwC, U);
  k_proj_q<<<dim3(BATCHN / RPB), dim3(256), 0, stream>>>(x, h, pwF, pbF, pwI, pbI,
                                                         pwO, pbO, pwC, pbC, U, qv);
  k_lstm<<<dim3(BATCHN / ROWS_LSTM), dim3(256), 0, stream>>>(qv, c, lwF, lbF, lwI, lbI,
                                                             lwO, lbO, lwC, lbC,
                                                             (float*)d_out);
}